// Round 1
// baseline (179.784 us; speedup 1.0000x reference)
//
#include <hip/hip_runtime.h>
#include <cstdint>
#include <cstddef>

// ---------------------------------------------------------------------------
// TripletFeatures: out[b,c,k] = S_mn * E[p+n,c] + (m!=n) * S_nm * E[p+m,c]
//   S_xy = sum_c E[p+x,c] * conj(E[p+x+y,c]),  E = E_real + i*E_imag, p=20
// Index list (m,n): m,n in [-20,20], |m*n|<=20, n>=m, |m|+|n|<=20,
// in (m outer asc, n inner asc) order — generated at compile time below.
// Output: (B, 2, K). Harness compares float32; primary variant writes the
// real part (out_size == B*2*K). If out_size == B*2*K*2, write interleaved
// (re,im) float2 = complex64.view(float32) layout.
// ---------------------------------------------------------------------------

namespace {

constexpr int MM   = 41;   // M
constexpr int HALF = 20;   // M//2
constexpr int LIM  = 20;   // RHO*L//2
constexpr int CAP  = 256;  // capacity upper bound for the index table

struct IdxTable {
    uint32_t v[CAP];
    int count;
};

constexpr IdxTable make_table() {
    IdxTable t{};
    int c = 0;
    for (int m = -HALF; m <= HALF; ++m) {
        for (int n = -HALF; n <= HALF; ++n) {
            int prod = m * n; if (prod < 0) prod = -prod;
            int am = m < 0 ? -m : m;
            int an = n < 0 ? -n : n;
            if (prod <= LIM && n >= m && (am + an) <= HALF) {
                uint32_t iu  = (uint32_t)(HALF + m);
                uint32_t iv  = (uint32_t)(HALF + n);
                uint32_t iw  = (uint32_t)(HALF + m + n);
                uint32_t sym = (m != n) ? 1u : 0u;
                t.v[c++] = iu | (iv << 8) | (iw << 16) | (sym << 24);
            }
        }
    }
    t.count = c;
    return t;
}

constexpr IdxTable HOST_TAB = make_table();
constexpr int K = HOST_TAB.count;              // = 173
static_assert(K > 0 && K <= CAP, "index table overflow");

} // namespace

__constant__ const IdxTable g_tab = make_table();

template <bool WRITE_COMPLEX>
__global__ __launch_bounds__(256)
void triplet_kernel(const float* __restrict__ Er, const float* __restrict__ Ei,
                    float* __restrict__ out, int B) {
    int t = blockIdx.x * blockDim.x + threadIdx.x;
    int total = B * K;
    if (t >= total) return;
    int b = t / K;
    int k = t - b * K;

    uint32_t e = g_tab.v[k];
    int iu = (int)(e & 0xffu);
    int iv = (int)((e >> 8) & 0xffu);
    int iw = (int)((e >> 16) & 0xffu);
    float symf = (e >> 24) ? 1.0f : 0.0f;

    // row base: 41 complex entries x 2 channels, stored as float2 per index
    const float2* rowr = reinterpret_cast<const float2*>(Er + (size_t)b * (2 * MM));
    const float2* rowi = reinterpret_cast<const float2*>(Ei + (size_t)b * (2 * MM));
    float2 ur = rowr[iu], uj = rowi[iu];   // U = E[p+m], channels (.x,.y)
    float2 vr = rowr[iv], vj = rowi[iv];   // V = E[p+n]
    float2 wr = rowr[iw], wj = rowi[iw];   // W = E[p+m+n]

    // S_mn = sum_c U_c * conj(W_c)
    float smn_r = ur.x * wr.x + uj.x * wj.x + ur.y * wr.y + uj.y * wj.y;
    float smn_i = uj.x * wr.x - ur.x * wj.x + uj.y * wr.y - ur.y * wj.y;
    // S_nm = sum_c V_c * conj(W_c)   (same W since m+n symmetric)
    float snm_r = vr.x * wr.x + vj.x * wj.x + vr.y * wr.y + vj.y * wj.y;
    float snm_i = vj.x * wr.x - vr.x * wj.x + vj.y * wr.y - vr.y * wj.y;
    snm_r *= symf;
    snm_i *= symf;

    // out[b,c,k] = S_mn * V_c + S_nm * U_c   (complex mult)
    float o0r = smn_r * vr.x - smn_i * vj.x + snm_r * ur.x - snm_i * uj.x;
    float o0i = smn_r * vj.x + smn_i * vr.x + snm_r * uj.x + snm_i * ur.x;
    float o1r = smn_r * vr.y - smn_i * vj.y + snm_r * ur.y - snm_i * uj.y;
    float o1i = smn_r * vj.y + smn_i * vr.y + snm_r * uj.y + snm_i * ur.y;

    if constexpr (WRITE_COMPLEX) {
        float2* o2 = reinterpret_cast<float2*>(out);
        o2[((size_t)b * 2 + 0) * K + k] = make_float2(o0r, o0i);
        o2[((size_t)b * 2 + 1) * K + k] = make_float2(o1r, o1i);
    } else {
        out[((size_t)b * 2 + 0) * K + k] = o0r;
        out[((size_t)b * 2 + 1) * K + k] = o1r;
    }
}

extern "C" void kernel_launch(void* const* d_in, const int* in_sizes, int n_in,
                              void* d_out, int out_size, void* d_ws, size_t ws_size,
                              hipStream_t stream) {
    const float* Er = (const float*)d_in[0];
    const float* Ei = (const float*)d_in[1];
    float* out = (float*)d_out;

    int B = in_sizes[0] / (2 * MM);           // (B, 41, 2) float32
    long total = (long)B * K;
    int block = 256;
    int grid = (int)((total + block - 1) / block);

    if ((long)out_size == (long)B * 2 * K * 2) {
        // complex64.view(float32) layout: (B, 2, K, 2) interleaved re/im
        triplet_kernel<true><<<grid, block, 0, stream>>>(Er, Ei, out, B);
    } else {
        // real part only: (B, 2, K) float32
        triplet_kernel<false><<<grid, block, 0, stream>>>(Er, Ei, out, B);
    }
}

// Round 2
// 129.622 us; speedup vs baseline: 1.3870x; 1.3870x over previous
//
#include <hip/hip_runtime.h>
#include <cstdint>
#include <cstddef>

// ---------------------------------------------------------------------------
// TripletFeatures: out[b,c,k] = S_mn * E[p+n,c] + (m!=n) * S_nm * E[p+m,c]
//   S_xy = sum_c E[p+x,c] * conj(E[p+x+y,c]),  E = E_real + i*E_imag, p=20
// R1: LDS-staged. Block stages NB=32 rows of E (float4 per entry:
// (Er0,Er1,Ei0,Ei1)) via coalesced float2 loads; each wave computes whole
// output rows with 3 ds_read_b128 per (b,k) item. Table offsets hoisted
// per-lane outside the row loop.
// ---------------------------------------------------------------------------

namespace {

constexpr int MM   = 41;   // M
constexpr int HALF = 20;   // M//2
constexpr int LIM  = 20;   // RHO*L//2
constexpr int CAP  = 256;

struct IdxTable {
    uint32_t v[CAP];
    int count;
};

constexpr IdxTable make_table() {
    IdxTable t{};
    int c = 0;
    for (int m = -HALF; m <= HALF; ++m) {
        for (int n = -HALF; n <= HALF; ++n) {
            int prod = m * n; if (prod < 0) prod = -prod;
            int am = m < 0 ? -m : m;
            int an = n < 0 ? -n : n;
            if (prod <= LIM && n >= m && (am + an) <= HALF) {
                uint32_t iu  = (uint32_t)(HALF + m);
                uint32_t iv  = (uint32_t)(HALF + n);
                uint32_t iw  = (uint32_t)(HALF + m + n);
                uint32_t sym = (m != n) ? 1u : 0u;
                t.v[c++] = iu | (iv << 8) | (iw << 16) | (sym << 24);
            }
        }
    }
    t.count = c;
    return t;
}

constexpr IdxTable HOST_TAB = make_table();
constexpr int K = HOST_TAB.count;              // = 173
static_assert(K > 0 && K <= CAP, "index table overflow");

constexpr int NB    = 32;                      // b-rows per block
constexpr int NWAVE = 4;                       // 256 threads
constexpr int KCH   = (K + 63) / 64;           // 3 k-slots per lane

} // namespace

__constant__ IdxTable g_tab = make_table();

template <bool WRITE_COMPLEX>
__global__ __launch_bounds__(256)
void triplet_kernel(const float2* __restrict__ Er2, const float2* __restrict__ Ei2,
                    float* __restrict__ out, int B) {
    __shared__ float4 sE[NB * MM];             // (b_local, i) -> (Er0,Er1,Ei0,Ei1)

    int b0 = blockIdx.x * NB;
    int rows = B - b0; if (rows > NB) rows = NB;
    int nent = rows * MM;
    int gbase = b0 * MM;                       // float2 index into (B,41) of float2

    for (int e = threadIdx.x; e < nent; e += 256) {
        float2 r  = Er2[gbase + e];
        float2 im = Ei2[gbase + e];
        sE[e] = make_float4(r.x, r.y, im.x, im.y);
    }
    __syncthreads();

    int lane = threadIdx.x & 63;
    int wave = threadIdx.x >> 6;

    // Hoist per-lane table decode: same k-slots reused for every row.
    int   offu[KCH], offv[KCH], offw[KCH];
    float symf[KCH];
    bool  act[KCH];
    #pragma unroll
    for (int j = 0; j < KCH; ++j) {
        int k = lane + 64 * j;
        act[j] = (k < K);
        uint32_t e = g_tab.v[act[j] ? k : 0];
        offu[j] = (int)(e & 0xffu);
        offv[j] = (int)((e >> 8) & 0xffu);
        offw[j] = (int)((e >> 16) & 0xffu);
        symf[j] = (e >> 24) ? 1.0f : 0.0f;
    }

    for (int bl = wave; bl < rows; bl += NWAVE) {
        const float4* sb = sE + bl * MM;
        size_t obase = (size_t)(b0 + bl) * 2 * K;
        #pragma unroll
        for (int j = 0; j < KCH; ++j) {
            if (!act[j]) continue;
            int k = lane + 64 * j;
            float4 u = sb[offu[j]];            // (Ur0,Ur1,Ui0,Ui1)
            float4 v = sb[offv[j]];
            float4 w = sb[offw[j]];

            float smn_r = u.x * w.x + u.z * w.z + u.y * w.y + u.w * w.w;
            float smn_i = u.z * w.x - u.x * w.z + u.w * w.y - u.y * w.w;
            float snm_r = (v.x * w.x + v.z * w.z + v.y * w.y + v.w * w.w) * symf[j];
            float snm_i = (v.z * w.x - v.x * w.z + v.w * w.y - v.y * w.w) * symf[j];

            float o0r = smn_r * v.x - smn_i * v.z + snm_r * u.x - snm_i * u.z;
            float o1r = smn_r * v.y - smn_i * v.w + snm_r * u.y - snm_i * u.w;

            if constexpr (WRITE_COMPLEX) {
                float o0i = smn_r * v.z + smn_i * v.x + snm_r * u.z + snm_i * u.x;
                float o1i = smn_r * v.w + smn_i * v.y + snm_r * u.w + snm_i * u.y;
                float2* o2 = reinterpret_cast<float2*>(out);
                o2[obase + k]     = make_float2(o0r, o0i);
                o2[obase + K + k] = make_float2(o1r, o1i);
            } else {
                out[obase + k]     = o0r;
                out[obase + K + k] = o1r;
            }
        }
    }
}

extern "C" void kernel_launch(void* const* d_in, const int* in_sizes, int n_in,
                              void* d_out, int out_size, void* d_ws, size_t ws_size,
                              hipStream_t stream) {
    const float2* Er2 = (const float2*)d_in[0];
    const float2* Ei2 = (const float2*)d_in[1];
    float* out = (float*)d_out;

    int B = in_sizes[0] / (2 * MM);            // (B, 41, 2) float32
    int grid = (B + NB - 1) / NB;
    int block = 256;

    if ((long)out_size == (long)B * 2 * K * 2) {
        triplet_kernel<true><<<grid, block, 0, stream>>>(Er2, Ei2, out, B);
    } else {
        triplet_kernel<false><<<grid, block, 0, stream>>>(Er2, Ei2, out, B);
    }
}